// Round 3
// baseline (526.084 us; speedup 1.0000x reference)
//
#include <hip/hip_runtime.h>
#include <hip/hip_bf16.h>
#include <math.h>

// Problem constants (GATConv, mode='mul', att='edge')
#define NN 50000
#define EE 800000
#define IN_F 128
#define NH 4
#define OUTD 16
#define EMB 32
#define EF 8
// derived
#define QK (NH*EMB)      // 128
#define FT (NH*OUTD)     // 64
#define ROW 320          // q(128) | k(128) | ft(64) per node

__device__ __forceinline__ void atomicMaxF(float* addr, float v) {
    if (v >= 0.0f) atomicMax((int*)addr, __float_as_int(v));
    else           atomicMin((unsigned int*)addr, __float_as_uint(v));
}

// ---------------- init: out = bias, emax = -inf, denom = 0 ----------------
__global__ __launch_bounds__(256) void init_kernel(float* __restrict__ out,
                                                   const float* __restrict__ bias,
                                                   float* __restrict__ emax,
                                                   float* __restrict__ denom,
                                                   int n) {
    int total = n * FT;
    for (int i = blockIdx.x * blockDim.x + threadIdx.x; i < total;
         i += gridDim.x * blockDim.x) {
        out[i] = bias[i & (FT - 1)];
        if (i < n * NH) { emax[i] = -INFINITY; denom[i] = 0.0f; }
    }
}

// ---------------- fused node projection: qkft[n][320] = feat @ [Wq|Wk|Wv] ---
#define NPB 32
__global__ __launch_bounds__(320) void proj_kernel(const float* __restrict__ feat,
                                                   const float* __restrict__ Wq,
                                                   const float* __restrict__ Wk,
                                                   const float* __restrict__ Wv,
                                                   float* __restrict__ qkft,
                                                   int n) {
    __shared__ float fs[NPB][IN_F];
    int node0 = blockIdx.x * NPB;
    int tid = threadIdx.x;  // 0..319
    for (int i = tid; i < NPB * IN_F; i += 320) {
        int nn = i >> 7, kk = i & 127;
        int g = node0 + nn;
        fs[nn][kk] = (g < n) ? feat[g * IN_F + kk] : 0.0f;
    }
    __syncthreads();

    int c = tid;  // output column 0..319
    const float* W; int col; int ldw;
    if (c < 128)      { W = Wq; col = c;       ldw = 128; }
    else if (c < 256) { W = Wk; col = c - 128; ldw = 128; }
    else              { W = Wv; col = c - 256; ldw = 64;  }

    float acc[NPB];
#pragma unroll
    for (int i = 0; i < NPB; i++) acc[i] = 0.0f;

    for (int k = 0; k < IN_F; k += 4) {
        float w0 = W[(k + 0) * ldw + col];
        float w1 = W[(k + 1) * ldw + col];
        float w2 = W[(k + 2) * ldw + col];
        float w3 = W[(k + 3) * ldw + col];
#pragma unroll
        for (int i = 0; i < NPB; i++) {
            float4 f = *(const float4*)&fs[i][k];
            acc[i] = fmaf(f.x, w0, fmaf(f.y, w1, fmaf(f.z, w2, fmaf(f.w, w3, acc[i]))));
        }
    }
    for (int i = 0; i < NPB; i++) {
        int g = node0 + i;
        if (g < n) qkft[g * ROW + c] = acc[i];
    }
}

// ---------------- edge pass 1: e[e][h] = sum_d q[s]*k[t]*ek, fused seg-max --
__global__ __launch_bounds__(256) void edge_e_kernel(const float* __restrict__ qkft,
                                                     const float* __restrict__ bond,
                                                     const int* __restrict__ src,
                                                     const int* __restrict__ dst,
                                                     const float* __restrict__ Wek,
                                                     const float* __restrict__ bek,
                                                     float* __restrict__ e_out,
                                                     float* __restrict__ emax,
                                                     int nE) {
    int gw = (blockIdx.x * 256 + threadIdx.x) >> 6;
    int lane = threadIdx.x & 63;
    int nw = (gridDim.x * 256) >> 6;

    // loop-invariant weight fragments (dims lane and lane+64)
    float wek0[EF], wek1[EF];
#pragma unroll
    for (int f = 0; f < EF; f++) {
        wek0[f] = Wek[f * QK + lane];
        wek1[f] = Wek[f * QK + 64 + lane];
    }
    float bk0 = bek[lane], bk1 = bek[64 + lane];

    for (int e = gw; e < nE; e += nw) {
        int s = src[e], t = dst[e];
        float b[EF];
#pragma unroll
        for (int f = 0; f < EF; f++) b[f] = bond[e * EF + f];

        float q0 = qkft[s * ROW + lane];
        float q1 = qkft[s * ROW + 64 + lane];
        float k0 = qkft[t * ROW + 128 + lane];
        float k1 = qkft[t * ROW + 192 + lane];

        float ek0 = bk0, ek1 = bk1;
#pragma unroll
        for (int f = 0; f < EF; f++) {
            ek0 = fmaf(b[f], wek0[f], ek0);
            ek1 = fmaf(b[f], wek1[f], ek1);
        }
        float p0 = q0 * k0 * ek0;   // dim = lane      -> head lane>>5 (0/1)
        float p1 = q1 * k1 * ek1;   // dim = lane+64   -> head 2+(lane>>5)
#pragma unroll
        for (int off = 16; off >= 1; off >>= 1) {
            p0 += __shfl_xor(p0, off);
            p1 += __shfl_xor(p1, off);
        }
        if (lane == 0) {
            e_out[e * NH + 0] = p0;
            e_out[e * NH + 2] = p1;
            atomicMaxF(&emax[t * NH + 0], p0);
            atomicMaxF(&emax[t * NH + 2], p1);
        } else if (lane == 32) {
            e_out[e * NH + 1] = p0;
            e_out[e * NH + 3] = p1;
            atomicMaxF(&emax[t * NH + 1], p0);
            atomicMaxF(&emax[t * NH + 3], p1);
        }
    }
}

// ---------------- edge pass 2: es = exp(e - emax[dst]); denom += es ---------
__global__ __launch_bounds__(256) void exp_sum_kernel(const int* __restrict__ dst,
                                                      const float* __restrict__ emax,
                                                      float* __restrict__ e_ws,
                                                      float* __restrict__ denom,
                                                      int total) {
    for (int i = blockIdx.x * blockDim.x + threadIdx.x; i < total;
         i += gridDim.x * blockDim.x) {
        int e = i >> 2, h = i & 3;
        int t = dst[e];
        float v = expf(e_ws[i] - emax[t * NH + h]);
        e_ws[i] = v;
        atomicAdd(&denom[t * NH + h], v);
    }
}

// ---------------- edge pass 3: scatter msg into out -------------------------
__global__ __launch_bounds__(256) void scatter_kernel(const float* __restrict__ qkft,
                                                      const float* __restrict__ bond,
                                                      const int* __restrict__ src,
                                                      const int* __restrict__ dst,
                                                      const float* __restrict__ Wef,
                                                      const float* __restrict__ bef,
                                                      const float* __restrict__ es,
                                                      const float* __restrict__ denom,
                                                      float* __restrict__ out,
                                                      int nE) {
    int gw = (blockIdx.x * 256 + threadIdx.x) >> 6;
    int lane = threadIdx.x & 63;     // lane = h*16 + o
    int nw = (gridDim.x * 256) >> 6;
    int h = lane >> 4;

    float wef[EF];
#pragma unroll
    for (int f = 0; f < EF; f++) wef[f] = Wef[f * FT + lane];
    float be = bef[lane];

    for (int e = gw; e < nE; e += nw) {
        int s = src[e], t = dst[e];
        float a = es[e * NH + h] / denom[t * NH + h];
        float ef = be;
#pragma unroll
        for (int f = 0; f < EF; f++) ef = fmaf(bond[e * EF + f], wef[f], ef);
        float m = qkft[s * ROW + 256 + lane] * ef * a;
        atomicAdd(&out[t * FT + lane], m);
    }
}

extern "C" void kernel_launch(void* const* d_in, const int* in_sizes, int n_in,
                              void* d_out, int out_size, void* d_ws, size_t ws_size,
                              hipStream_t stream) {
    const float* feat = (const float*)d_in[0];
    const float* bond = (const float*)d_in[1];
    const int*   src  = (const int*)d_in[2];
    const int*   dst  = (const int*)d_in[3];
    const float* Wq   = (const float*)d_in[4];
    const float* Wk   = (const float*)d_in[5];
    const float* Wv   = (const float*)d_in[6];
    const float* Wek  = (const float*)d_in[7];
    const float* bek  = (const float*)d_in[8];
    const float* Wef  = (const float*)d_in[9];
    const float* bef  = (const float*)d_in[10];
    const float* bias = (const float*)d_in[11];
    float* out = (float*)d_out;

    const int n = in_sizes[0] / IN_F;   // 50000
    const int nE = in_sizes[2];         // 800000

    float* ws    = (float*)d_ws;
    float* qkft  = ws;                         // n*320
    float* e_ws  = qkft + (size_t)n * ROW;     // nE*4
    float* emax  = e_ws + (size_t)nE * NH;     // n*4
    float* denom = emax + (size_t)n * NH;      // n*4

    init_kernel<<<2048, 256, 0, stream>>>(out, bias, emax, denom, n);
    proj_kernel<<<(n + NPB - 1) / NPB, 320, 0, stream>>>(feat, Wq, Wk, Wv, qkft, n);
    edge_e_kernel<<<8192, 256, 0, stream>>>(qkft, bond, src, dst, Wek, bek, e_ws, emax, nE);
    exp_sum_kernel<<<2048, 256, 0, stream>>>(dst, emax, e_ws, denom, nE * NH);
    scatter_kernel<<<8192, 256, 0, stream>>>(qkft, bond, src, dst, Wef, bef, e_ws, denom, out, nE);
}

// Round 4
// 459.732 us; speedup vs baseline: 1.1443x; 1.1443x over previous
//
#include <hip/hip_runtime.h>
#include <hip/hip_bf16.h>
#include <math.h>

// GATConv (mode='mul', att='edge') on MI355X
#define NN 50000
#define EE 800000
#define IN_F 128
#define NH 4
#define OUTD 16
#define EMB 32
#define EF 8
#define QK (NH*EMB)      // 128
#define FT (NH*OUTD)     // 64
// packed bf16 node row: q dims 0..127 in ushorts 0..127, k dims in 128..255
#define QKROW 256

__device__ __forceinline__ void atomicMaxF(float* addr, float v) {
    if (v >= 0.0f) atomicMax((int*)addr, __float_as_int(v));
    else           atomicMin((unsigned int*)addr, __float_as_uint(v));
}

__device__ __forceinline__ unsigned short f2bf(float x) {
    unsigned int u = __float_as_uint(x);
    u += 0x7fffu + ((u >> 16) & 1u);   // round-to-nearest-even
    return (unsigned short)(u >> 16);
}
__device__ __forceinline__ float bf2f(unsigned int hi16) {
    return __uint_as_float(hi16 << 16);
}

// ---------------- init: out = bias, emax = -inf, denom = 0 ----------------
__global__ __launch_bounds__(256) void init_kernel(float* __restrict__ out,
                                                   const float* __restrict__ bias,
                                                   float* __restrict__ emax,
                                                   float* __restrict__ denom,
                                                   int n) {
    int total = n * FT;
    for (int i = blockIdx.x * blockDim.x + threadIdx.x; i < total;
         i += gridDim.x * blockDim.x) {
        out[i] = bias[i & (FT - 1)];
        if (i < n * NH) { emax[i] = -INFINITY; denom[i] = 0.0f; }
    }
}

// ------- fused projection: qk_bf16[n][256], ft_bf16[n][64] from feat -------
#define NPB 32
__global__ __launch_bounds__(320) void proj_kernel(const float* __restrict__ feat,
                                                   const float* __restrict__ Wq,
                                                   const float* __restrict__ Wk,
                                                   const float* __restrict__ Wv,
                                                   unsigned short* __restrict__ qkh,
                                                   unsigned short* __restrict__ fth,
                                                   int n) {
    __shared__ float fs[NPB][IN_F];
    int node0 = blockIdx.x * NPB;
    int tid = threadIdx.x;  // 0..319
    for (int i = tid; i < NPB * IN_F; i += 320) {
        int nn = i >> 7, kk = i & 127;
        int g = node0 + nn;
        fs[nn][kk] = (g < n) ? feat[g * IN_F + kk] : 0.0f;
    }
    __syncthreads();

    int c = tid;  // output column 0..319
    const float* W; int col; int ldw;
    if (c < 128)      { W = Wq; col = c;       ldw = 128; }
    else if (c < 256) { W = Wk; col = c - 128; ldw = 128; }
    else              { W = Wv; col = c - 256; ldw = 64;  }

    float acc[NPB];
#pragma unroll
    for (int i = 0; i < NPB; i++) acc[i] = 0.0f;

    for (int k = 0; k < IN_F; k += 4) {
        float w0 = W[(k + 0) * ldw + col];
        float w1 = W[(k + 1) * ldw + col];
        float w2 = W[(k + 2) * ldw + col];
        float w3 = W[(k + 3) * ldw + col];
#pragma unroll
        for (int i = 0; i < NPB; i++) {
            float4 f = *(const float4*)&fs[i][k];
            acc[i] = fmaf(f.x, w0, fmaf(f.y, w1, fmaf(f.z, w2, fmaf(f.w, w3, acc[i]))));
        }
    }
    for (int i = 0; i < NPB; i++) {
        int g = node0 + i;
        if (g >= n) break;
        unsigned short v = f2bf(acc[i]);
        if (c < 256) qkh[(size_t)g * QKROW + c] = v;       // q cols 0..127, k cols 128..255
        else         fth[(size_t)g * FT + (c - 256)] = v;  // ft cols 0..63
    }
}

// ---- edge pass 1: e[e][h] = sum_d q[s]d * k[t]d * ek_d, fused seg-max -----
// lane i handles dims (2i, 2i+1); head = i>>4; 16-lane-group reduce.
__global__ __launch_bounds__(256) void edge_e_kernel(const unsigned int* __restrict__ qk32,
                                                     const float* __restrict__ bond,
                                                     const int* __restrict__ src,
                                                     const int* __restrict__ dst,
                                                     const float* __restrict__ Wek,
                                                     const float* __restrict__ bek,
                                                     float* __restrict__ e_out,
                                                     float* __restrict__ emax,
                                                     int nE) {
    int gw = (blockIdx.x * 256 + threadIdx.x) >> 6;
    int lane = threadIdx.x & 63;
    int nw = (gridDim.x * 256) >> 6;
    int d0 = 2 * lane;            // dims d0, d0+1
    int h = lane >> 4;            // head of both dims

    float wek0[EF], wek1[EF];
#pragma unroll
    for (int f = 0; f < EF; f++) {
        wek0[f] = Wek[f * QK + d0];
        wek1[f] = Wek[f * QK + d0 + 1];
    }
    float bk0 = bek[d0], bk1 = bek[d0 + 1];

    for (int e = gw; e < nE; e += nw) {
        int s = src[e], t = dst[e];
        float b[EF];
#pragma unroll
        for (int f = 0; f < EF; f++) b[f] = bond[e * EF + f];

        unsigned int qv = qk32[(size_t)s * 128 + lane];       // q dims 2l,2l+1
        unsigned int kv = qk32[(size_t)t * 128 + 64 + lane];  // k dims 2l,2l+1
        float q0 = bf2f(qv & 0xffffu), q1 = bf2f(qv >> 16);
        float k0 = bf2f(kv & 0xffffu), k1 = bf2f(kv >> 16);

        float ek0 = bk0, ek1 = bk1;
#pragma unroll
        for (int f = 0; f < EF; f++) {
            ek0 = fmaf(b[f], wek0[f], ek0);
            ek1 = fmaf(b[f], wek1[f], ek1);
        }
        float p = fmaf(q0 * k0, ek0, q1 * k1 * ek1);
#pragma unroll
        for (int off = 8; off >= 1; off >>= 1)
            p += __shfl_xor(p, off);          // reduce within 16-lane head group
        if ((lane & 15) == 0) {
            e_out[e * NH + h] = p;
            atomicMaxF(&emax[t * NH + h], p);
        }
    }
}

// ---------------- edge pass 2: es = exp(e - emax[dst]); denom += es ---------
__global__ __launch_bounds__(256) void exp_sum_kernel(const int* __restrict__ dst,
                                                      const float* __restrict__ emax,
                                                      float* __restrict__ e_ws,
                                                      float* __restrict__ denom,
                                                      int total) {
    for (int i = blockIdx.x * blockDim.x + threadIdx.x; i < total;
         i += gridDim.x * blockDim.x) {
        int e = i >> 2, h = i & 3;
        int t = dst[e];
        float v = expf(e_ws[i] - emax[t * NH + h]);
        e_ws[i] = v;
        atomicAdd(&denom[t * NH + h], v);
    }
}

// ---------------- edge pass 3: scatter msg into out -------------------------
__global__ __launch_bounds__(256) void scatter_kernel(const unsigned short* __restrict__ fth,
                                                      const float* __restrict__ bond,
                                                      const int* __restrict__ src,
                                                      const int* __restrict__ dst,
                                                      const float* __restrict__ Wef,
                                                      const float* __restrict__ bef,
                                                      const float* __restrict__ es,
                                                      const float* __restrict__ denom,
                                                      float* __restrict__ out,
                                                      int nE) {
    int gw = (blockIdx.x * 256 + threadIdx.x) >> 6;
    int lane = threadIdx.x & 63;     // lane = h*16 + o
    int nw = (gridDim.x * 256) >> 6;
    int h = lane >> 4;

    float wef[EF];
#pragma unroll
    for (int f = 0; f < EF; f++) wef[f] = Wef[f * FT + lane];
    float be = bef[lane];

    for (int e = gw; e < nE; e += nw) {
        int s = src[e], t = dst[e];
        float a = es[e * NH + h] / denom[t * NH + h];
        float ef = be;
#pragma unroll
        for (int f = 0; f < EF; f++) ef = fmaf(bond[e * EF + f], wef[f], ef);
        float ftv = bf2f((unsigned int)fth[(size_t)s * FT + lane]);
        float m = ftv * ef * a;
        atomicAdd(&out[t * FT + lane], m);
    }
}

extern "C" void kernel_launch(void* const* d_in, const int* in_sizes, int n_in,
                              void* d_out, int out_size, void* d_ws, size_t ws_size,
                              hipStream_t stream) {
    const float* feat = (const float*)d_in[0];
    const float* bond = (const float*)d_in[1];
    const int*   src  = (const int*)d_in[2];
    const int*   dst  = (const int*)d_in[3];
    const float* Wq   = (const float*)d_in[4];
    const float* Wk   = (const float*)d_in[5];
    const float* Wv   = (const float*)d_in[6];
    const float* Wek  = (const float*)d_in[7];
    const float* bek  = (const float*)d_in[8];
    const float* Wef  = (const float*)d_in[9];
    const float* bef  = (const float*)d_in[10];
    const float* bias = (const float*)d_in[11];
    float* out = (float*)d_out;

    const int n = in_sizes[0] / IN_F;   // 50000
    const int nE = in_sizes[2];         // 800000

    // workspace layout
    unsigned int* qk32 = (unsigned int*)d_ws;                    // n*128 uints (bf16 q|k)
    unsigned short* fth = (unsigned short*)(qk32 + (size_t)n * 128); // n*64 ushorts
    float* e_ws  = (float*)(fth + (size_t)n * FT);               // nE*4
    float* emax  = e_ws + (size_t)nE * NH;                       // n*4
    float* denom = emax + (size_t)n * NH;                        // n*4

    init_kernel<<<2048, 256, 0, stream>>>(out, bias, emax, denom, n);
    proj_kernel<<<(n + NPB - 1) / NPB, 320, 0, stream>>>(
        feat, Wq, Wk, Wv, (unsigned short*)qk32, fth, n);
    edge_e_kernel<<<8192, 256, 0, stream>>>(qk32, bond, src, dst, Wek, bek, e_ws, emax, nE);
    exp_sum_kernel<<<2048, 256, 0, stream>>>(dst, emax, e_ws, denom, nE * NH);
    scatter_kernel<<<8192, 256, 0, stream>>>(fth, bond, src, dst, Wef, bef, e_ws, denom, out, nE);
}